// Round 3
// baseline (119.603 us; speedup 1.0000x reference)
//
#include <hip/hip_runtime.h>
#include <hip/hip_bf16.h>
#include <math.h>

#define H_DIM 288
#define NHEADS 18
#define HEAD_D 16
#define SEQ 2048
#define BATCH 2
#define M_TOT (BATCH*SEQ)       // 4096
#define XCNT (M_TOT*H_DIM)      // 1179648
#define WCNT (H_DIM*H_DIM)      // 82944
#define NUNITS 10368            // 36 bh x 288 (qp,chunk) split-K units
#define NUU    20736            // units split by q-tile (2 waves per unit)
#define NQUNITS 2304            // 36 bh x 64 qp

typedef _Float16 f16_t;
typedef __attribute__((ext_vector_type(2))) _Float16 half2v;
typedef __attribute__((ext_vector_type(4))) _Float16 half4v;
typedef __attribute__((ext_vector_type(8))) _Float16 half8v;
typedef __attribute__((ext_vector_type(4))) float   float4v;

// ---------------------------------------------------------------------------
// K0: fp32 -> f16 convert: X (4096x288) and the four 288x288 weights.
// ---------------------------------------------------------------------------
__global__ __launch_bounds__(256) void cvt_f16(
    const float* __restrict__ X,
    const float* __restrict__ Wq, const float* __restrict__ Wk,
    const float* __restrict__ Wv, const float* __restrict__ Wo,
    f16_t* __restrict__ Xf, f16_t* __restrict__ Wf)
{
    int idx = blockIdx.x * 256 + threadIdx.x;
    const int X4 = XCNT/4, W4 = WCNT/4;
    if (idx >= X4 + 4*W4) return;
    const float* src; f16_t* dst; int off;
    if (idx < X4) { src = X; dst = Xf; off = idx; }
    else {
        int r = idx - X4;
        int wz = r / W4; off = r - wz*W4;
        src = (wz==0) ? Wq : (wz==1) ? Wk : (wz==2) ? Wv : Wo;
        dst = Wf + (size_t)wz*WCNT;
    }
    float4 v = ((const float4*)src)[off];
    half4v h; h[0]=(f16_t)v.x; h[1]=(f16_t)v.y; h[2]=(f16_t)v.z; h[3]=(f16_t)v.w;
    ((half4v*)dst)[off] = h;
}

// ---------------------------------------------------------------------------
// K1: QKV projection via MFMA 16x16x32 f16. R17: tile M=16 x N=48 (was
// M=32): 4608 one-wave blocks instead of 2304 — double the independent
// waves for this latency-bound phase; same total MFMA work, B-tiles
// re-read from L2.
// Epilogue: Q,K -> RoPE -> f16 [b,h,s,d]; Q pre-scaled 0.25*log2(e).
// V -> f16 tiled Vt[bh][s>>4][d][s&15].
// ---------------------------------------------------------------------------
__global__ __launch_bounds__(64) void qkv_mfma(
    const f16_t* __restrict__ Xf, const f16_t* __restrict__ Wf,
    f16_t* __restrict__ Q16, f16_t* __restrict__ K16, f16_t* __restrict__ Vt)
{
    const int bx = blockIdx.x;          // 0..17
    const int z  = bx/6;
    const int n0 = (bx - z*6)*48;
    const int m0 = blockIdx.y*16;       // grid.y = 256
    const int lane = threadIdx.x & 63;
    const int n = lane & 15, quad = lane >> 4;

    const f16_t* W = Wf + (size_t)z*WCNT;

    float4v acc[3];
    #pragma unroll
    for (int nt = 0; nt < 3; nt++)
        acc[nt] = (float4v){0.f,0.f,0.f,0.f};

    for (int k0 = 0; k0 < H_DIM; k0 += 32) {
        half8v a = *(const half8v*)(Xf + (size_t)(m0 + n)*H_DIM + k0 + quad*8);
        half8v b[3];
        #pragma unroll
        for (int nt = 0; nt < 3; nt++)
            b[nt] = *(const half8v*)(W + (size_t)(n0 + nt*16 + n)*H_DIM + k0 + quad*8);
        #pragma unroll
        for (int nt = 0; nt < 3; nt++)
            acc[nt] = __builtin_amdgcn_mfma_f32_16x16x32_f16(a, b[nt], acc[nt], 0, 0, 0);
    }

    if (z < 2) {   // Q or K: RoPE epilogue
        f16_t* dst = (z == 0) ? Q16 : K16;
        // invf in revolutions: theta^{-(d%8)/8} / (2*pi)
        const float invf_rev = exp2f(-1.6609640474436813f * (float)(n & 7))
                             * 0.15915494309189535f;
        #pragma unroll
        for (int r = 0; r < 4; r++) {
            int m = m0 + quad*4 + r;
            int bb = m >> 11, s = m & (SEQ - 1);
            float rev = (float)s * invf_rev;
            float fr = rev - floorf(rev);
            float sn = __builtin_amdgcn_sinf(fr);   // sin(2*pi*fr)
            float c  = __builtin_amdgcn_cosf(fr);
            #pragma unroll
            for (int nt = 0; nt < 3; nt++) {
                float own = acc[nt][r];
                float par = __shfl_xor(own, 8, 64);
                float val = (n & 8) ? fmaf(own, c, par*sn) : fmaf(own, c, -par*sn);
                if (z == 0) val *= 0.36067376022224085f;  // 0.25 * log2(e)
                int head = (n0 >> 4) + nt;
                dst[((size_t)((bb*NHEADS + head)*SEQ) + s)*HEAD_D + n] = (f16_t)val;
            }
        }
    } else {       // V: transposed tiled store
        #pragma unroll
        for (int nt = 0; nt < 3; nt++)
            #pragma unroll
            for (int r = 0; r < 4; r++) {
                int m = m0 + quad*4 + r;
                int bb = m >> 11, s = m & (SEQ - 1);
                int head = (n0 >> 4) + nt;
                Vt[(size_t)(bb*NHEADS + head)*(SEQ*HEAD_D)
                   + (size_t)(s >> 4)*256 + n*16 + (s & 15)] = (f16_t)acc[nt][r];
            }
    }
}

__device__ __forceinline__ half4v pack4(const float p[4]) {
    half2v ab = __builtin_bit_cast(half2v, __builtin_amdgcn_cvt_pkrtz(p[0], p[1]));
    half2v cd = __builtin_bit_cast(half2v, __builtin_amdgcn_cvt_pkrtz(p[2], p[3]));
    half4v o; o[0]=ab[0]; o[1]=ab[1]; o[2]=cd[0]; o[3]=cd[1];
    return o;
}

// ---------------------------------------------------------------------------
// K2 (R17): flash attention split-K partials, one wave per (unit, q-tile).
// vs R15: each of the 10368 (bh,qp,chunk) units is now TWO waves (one per
// 16-query tile) -> 20736 waves (2x TLP), identical partial layout/volume.
// Bulk path stages K/V in 2 sequential batches of 8 (32 VGPR vs 64): lower
// register pressure -> ~8 resident waves/SIMD (was ~5); the mid-chunk load
// stall is hidden by the extra resident waves. R16 proved this phase is
// parallelism-bound (fusing to 2304 waves regressed), so TLP is the lever.
// XCD-contiguous swizzle (5184 blocks % 8 == 0, bijective) keeps each XCD
// on a contiguous bh range (K/V L2-resident); adjacent uu pairs share the
// same K/V chunk.
// ---------------------------------------------------------------------------
__global__ __launch_bounds__(256) void attn_part(
    const f16_t* __restrict__ Q16, const f16_t* __restrict__ K16,
    const f16_t* __restrict__ Vt,
    float4* __restrict__ accbuf, float* __restrict__ lbuf)
{
    const int bid = blockIdx.x;                       // 0..5183
    const int swz = (bid & 7) * 648 + (bid >> 3);     // XCD-contiguous remap
    const int uu  = swz*4 + (threadIdx.x >> 6);       // 0..20735
    const int unit = uu >> 1, tq = uu & 1;
    const int lane = threadIdx.x & 63;
    const int n = lane & 15, quad = lane >> 4;

    const int bh = unit / 288;
    const int rem = unit - bh*288;
    int g, t0;
    if      (rem < 8)   { g=0; t0=rem;     }
    else if (rem < 24)  { g=1; t0=rem-8;   }
    else if (rem < 48)  { g=2; t0=rem-24;  }
    else if (rem < 80)  { g=3; t0=rem-48;  }
    else if (rem < 120) { g=4; t0=rem-80;  }
    else if (rem < 168) { g=5; t0=rem-120; }
    else if (rem < 224) { g=6; t0=rem-168; }
    else                { g=7; t0=rem-224; }
    const int qd = t0 / (g+1);
    const int qp = 8*g + qd;
    const int chunk = t0 - qd*(g+1);

    half4v qb = *(const half4v*)(Q16 + ((size_t)bh*SEQ + qp*32 + tq*16 + n)*HEAD_D + quad*4);
    const f16_t* Kb = K16 + (size_t)bh * SEQ * HEAD_D;
    const f16_t* Vb = Vt  + (size_t)bh * SEQ * HEAD_D;
    const int loff = n*16 + quad*4;

    const float4v zero = {0.f, 0.f, 0.f, 0.f};
    float4v acc = zero;
    float l = 0.f;

    const int lim  = 2*qp + tq;          // last allowed k-tile (diagonal)
    const int ktlo = chunk*16;
    const int kthi = min(ktlo + 15, lim);

    if (ktlo + 15 < lim) {
        // bulk: full 16-tile chunk, no masking; 2 register batches of 8
        #pragma unroll 1
        for (int hb = 0; hb < 2; hb++) {
            const int kb = ktlo + hb*8;
            half4v KA[8], VA[8];
            #pragma unroll
            for (int i = 0; i < 8; i++) {
                KA[i] = *(const half4v*)(Kb + (size_t)(kb + i)*256 + loff);
                VA[i] = *(const half4v*)(Vb + (size_t)(kb + i)*256 + loff);
            }
            __builtin_amdgcn_s_setprio(1);
            #pragma unroll
            for (int i = 0; i < 8; i++) {
                float4v s = __builtin_amdgcn_mfma_f32_16x16x16f16(KA[i], qb, zero, 0, 0, 0);
                float p[4];
                #pragma unroll
                for (int r = 0; r < 4; r++) p[r] = __builtin_amdgcn_exp2f(s[r]);
                l += (p[0]+p[1]) + (p[2]+p[3]);
                acc = __builtin_amdgcn_mfma_f32_16x16x16f16(VA[i], pack4(p), acc, 0, 0, 0);
            }
            __builtin_amdgcn_s_setprio(0);
        }
    } else {
        // tail chunk with causal masking at kt == lim
        int kt = ktlo;
        half4v ka = *(const half4v*)(Kb + (size_t)kt*256 + loff);
        half4v va = *(const half4v*)(Vb + (size_t)kt*256 + loff);
        for (; kt <= kthi; kt++) {
            half4v kan, van;
            if (kt < kthi) {
                kan = *(const half4v*)(Kb + (size_t)(kt+1)*256 + loff);
                van = *(const half4v*)(Vb + (size_t)(kt+1)*256 + loff);
            }
            float4v s = __builtin_amdgcn_mfma_f32_16x16x16f16(ka, qb, zero, 0, 0, 0);
            float p[4];
            #pragma unroll
            for (int r = 0; r < 4; r++) {
                float e = __builtin_amdgcn_exp2f(s[r]);
                p[r] = (kt == lim && quad*4 + r > n) ? 0.0f : e;
            }
            l += (p[0]+p[1]) + (p[2]+p[3]);
            acc = __builtin_amdgcn_mfma_f32_16x16x16f16(va, pack4(p), acc, 0, 0, 0);
            ka = kan; va = van;
        }
    }

    float4 a0; a0.x=acc[0]; a0.y=acc[1]; a0.z=acc[2]; a0.w=acc[3];
    accbuf[((size_t)unit*2 + tq)*64 + lane] = a0;
    lbuf  [((size_t)unit*2 + tq)*64 + lane] = l;
}

// ---------------------------------------------------------------------------
// K3: reduction: one wave per (bh, qp) sums <=8 chunk partials, normalizes,
// writes f16 O. R15-proven: XCD remap matching attn_part; fixed-8 unrolled
// index-clamped mask-multiplied loads (all in flight at once; clamped index
// always targets a written partial, so poison never enters).
// ---------------------------------------------------------------------------
__global__ __launch_bounds__(256) void attn_red(
    const float4* __restrict__ accbuf, const float* __restrict__ lbuf,
    f16_t* __restrict__ Of)
{
    const int bid = blockIdx.x;                       // 0..575
    const int swz = (bid & 7) * 72 + (bid >> 3);
    const int wid = swz*4 + (threadIdx.x >> 6);       // 0..2303
    const int lane = threadIdx.x & 63;
    const int n = lane & 15, quad = lane >> 4;
    const int bh = wid >> 6, qp = wid & 63;
    const int b = bh / NHEADS, h = bh - b*NHEADS;
    const int g = qp >> 3, j = qp & 7;
    const int nch = g + 1;
    const int ubase = bh*288 + qp + 4*g*(g-1) + g*j;

    #pragma unroll
    for (int t = 0; t < 2; t++) {
        float4 a = {0.f, 0.f, 0.f, 0.f};
        float l = 0.f;
        #pragma unroll
        for (int c = 0; c < 8; c++) {
            const int  cc = (c < nch) ? c : (nch - 1);
            const float m = (c < nch) ? 1.0f : 0.0f;
            size_t idx = ((size_t)(ubase + cc)*2 + t)*64 + lane;
            float4 v = accbuf[idx];
            float lv = lbuf[idx];
            a.x = fmaf(v.x, m, a.x); a.y = fmaf(v.y, m, a.y);
            a.z = fmaf(v.z, m, a.z); a.w = fmaf(v.w, m, a.w);
            l   = fmaf(lv,  m, l);
        }
        l += __shfl_xor(l, 16, 64);
        l += __shfl_xor(l, 32, 64);
        float inv = 1.0f / l;
        half4v o;
        o[0]=(f16_t)(a.x*inv); o[1]=(f16_t)(a.y*inv);
        o[2]=(f16_t)(a.z*inv); o[3]=(f16_t)(a.w*inv);
        *(half4v*)(Of + (size_t)(b*SEQ + qp*32 + t*16 + n)*H_DIM + h*HEAD_D + quad*4) = o;
    }
}

// ---------------------------------------------------------------------------
// K4: output projection via MFMA (R9-proven). Tile M=32 x N=48, grid (6,128).
// ---------------------------------------------------------------------------
__global__ __launch_bounds__(64) void out_mfma(
    const f16_t* __restrict__ Of, const f16_t* __restrict__ Wo16,
    float* __restrict__ C)
{
    const int n0 = blockIdx.x * 48;
    const int m0 = blockIdx.y * 32;
    const int lane = threadIdx.x & 63;
    const int n = lane & 15, quad = lane >> 4;

    float4v acc[2][3];
    #pragma unroll
    for (int mt = 0; mt < 2; mt++)
        #pragma unroll
        for (int nt = 0; nt < 3; nt++)
            acc[mt][nt] = (float4v){0.f,0.f,0.f,0.f};

    for (int k0 = 0; k0 < H_DIM; k0 += 32) {
        half8v a[2], b[3];
        #pragma unroll
        for (int mt = 0; mt < 2; mt++)
            a[mt] = *(const half8v*)(Of + (size_t)(m0 + mt*16 + n)*H_DIM + k0 + quad*8);
        #pragma unroll
        for (int nt = 0; nt < 3; nt++)
            b[nt] = *(const half8v*)(Wo16 + (size_t)(n0 + nt*16 + n)*H_DIM + k0 + quad*8);
        #pragma unroll
        for (int mt = 0; mt < 2; mt++)
            #pragma unroll
            for (int nt = 0; nt < 3; nt++)
                acc[mt][nt] = __builtin_amdgcn_mfma_f32_16x16x32_f16(a[mt], b[nt], acc[mt][nt], 0, 0, 0);
    }
    #pragma unroll
    for (int mt = 0; mt < 2; mt++)
        #pragma unroll
        for (int nt = 0; nt < 3; nt++)
            #pragma unroll
            for (int r = 0; r < 4; r++) {
                int m = m0 + mt*16 + quad*4 + r;
                C[(size_t)m*H_DIM + n0 + nt*16 + n] = acc[mt][nt][r];
            }
}

// ---------------------------------------------------------------------------
extern "C" void kernel_launch(void* const* d_in, const int* in_sizes, int n_in,
                              void* d_out, int out_size, void* d_ws, size_t ws_size,
                              hipStream_t stream)
{
    const float* Xh = (const float*)d_in[0];
    const float* Wq = (const float*)d_in[1];
    const float* Wk = (const float*)d_in[2];
    const float* Wv = (const float*)d_in[3];
    const float* Wo = (const float*)d_in[4];
    float* out = (float*)d_out;

    f16_t* Xf  = (f16_t*)d_ws;                  // XCNT
    f16_t* Wf  = Xf + XCNT;                     // 4*WCNT
    f16_t* Q16 = Wf + 4*(size_t)WCNT;           // XCNT
    f16_t* K16 = Q16 + XCNT;                    // XCNT
    f16_t* Vt  = K16 + XCNT;                    // XCNT
    f16_t* Of  = Vt + XCNT;                     // XCNT
    float4* accbuf = (float4*)(Of + XCNT);      // NUNITS*2*64 float4
    float*  lbuf   = (float*)(accbuf + (size_t)NUNITS*2*64);

    const int total4 = (XCNT + 4*WCNT)/4;
    cvt_f16<<<dim3((total4 + 255)/256), 256, 0, stream>>>(Xh, Wq, Wk, Wv, Wo, Xf, Wf);
    qkv_mfma<<<dim3(18, 256), 64, 0, stream>>>(Xf, Wf, Q16, K16, Vt);
    attn_part<<<dim3(NUU/4), 256, 0, stream>>>(Q16, K16, Vt, accbuf, lbuf);
    attn_red<<<dim3(NQUNITS/4), 256, 0, stream>>>(accbuf, lbuf, Of);
    out_mfma<<<dim3(6, 128), 64, 0, stream>>>(Of, Wf + 3*(size_t)WCNT, out);
}

// Round 4
// 112.326 us; speedup vs baseline: 1.0648x; 1.0648x over previous
//
#include <hip/hip_runtime.h>
#include <hip/hip_bf16.h>
#include <math.h>

#define H_DIM 288
#define NHEADS 18
#define HEAD_D 16
#define SEQ 2048
#define BATCH 2
#define M_TOT (BATCH*SEQ)       // 4096
#define XCNT (M_TOT*H_DIM)      // 1179648
#define WCNT (H_DIM*H_DIM)      // 82944
#define NUNITS 10368            // 36 bh x 288 (qp,chunk) split-K units
#define NQUNITS 2304            // 36 bh x 64 qp

typedef _Float16 f16_t;
typedef __attribute__((ext_vector_type(2))) _Float16 half2v;
typedef __attribute__((ext_vector_type(4))) _Float16 half4v;
typedef __attribute__((ext_vector_type(8))) _Float16 half8v;
typedef __attribute__((ext_vector_type(4))) float   float4v;

// ---------------------------------------------------------------------------
// K0: fp32 -> f16 convert: X (4096x288) and the four 288x288 weights.
// ---------------------------------------------------------------------------
__global__ __launch_bounds__(256) void cvt_f16(
    const float* __restrict__ X,
    const float* __restrict__ Wq, const float* __restrict__ Wk,
    const float* __restrict__ Wv, const float* __restrict__ Wo,
    f16_t* __restrict__ Xf, f16_t* __restrict__ Wf)
{
    int idx = blockIdx.x * 256 + threadIdx.x;
    const int X4 = XCNT/4, W4 = WCNT/4;
    if (idx >= X4 + 4*W4) return;
    const float* src; f16_t* dst; int off;
    if (idx < X4) { src = X; dst = Xf; off = idx; }
    else {
        int r = idx - X4;
        int wz = r / W4; off = r - wz*W4;
        src = (wz==0) ? Wq : (wz==1) ? Wk : (wz==2) ? Wv : Wo;
        dst = Wf + (size_t)wz*WCNT;
    }
    float4 v = ((const float4*)src)[off];
    half4v h; h[0]=(f16_t)v.x; h[1]=(f16_t)v.y; h[2]=(f16_t)v.z; h[3]=(f16_t)v.w;
    ((half4v*)dst)[off] = h;
}

// ---------------------------------------------------------------------------
// K1: QKV projection via MFMA 16x16x32 f16 (R9-proven tiling). One wave per
// block, tile M=32 x N=48, grid (18,128).
// Epilogue: Q,K -> RoPE -> f16 [b,h,s,d]; Q pre-scaled 0.25*log2(e) so the
// attention softmax can use raw exp2.
// RoPE sin/cos via HW v_sin/v_cos in REVOLUTIONS with explicit fract range
// reduction (replaces libm sincosf's slow large-arg path; err ~1e-4 rad).
// V -> f16 tiled Vt[bh][s>>4][d][s&15].
// ---------------------------------------------------------------------------
__global__ __launch_bounds__(64) void qkv_mfma(
    const f16_t* __restrict__ Xf, const f16_t* __restrict__ Wf,
    f16_t* __restrict__ Q16, f16_t* __restrict__ K16, f16_t* __restrict__ Vt)
{
    const int bx = blockIdx.x;          // 0..17
    const int z  = bx/6;
    const int n0 = (bx - z*6)*48;
    const int m0 = blockIdx.y*32;
    const int lane = threadIdx.x & 63;
    const int n = lane & 15, quad = lane >> 4;

    const f16_t* W = Wf + (size_t)z*WCNT;

    float4v acc[2][3];
    #pragma unroll
    for (int mt = 0; mt < 2; mt++)
        #pragma unroll
        for (int nt = 0; nt < 3; nt++)
            acc[mt][nt] = (float4v){0.f,0.f,0.f,0.f};

    for (int k0 = 0; k0 < H_DIM; k0 += 32) {
        half8v a[2], b[3];
        #pragma unroll
        for (int mt = 0; mt < 2; mt++)
            a[mt] = *(const half8v*)(Xf + (size_t)(m0 + mt*16 + n)*H_DIM + k0 + quad*8);
        #pragma unroll
        for (int nt = 0; nt < 3; nt++)
            b[nt] = *(const half8v*)(W + (size_t)(n0 + nt*16 + n)*H_DIM + k0 + quad*8);
        #pragma unroll
        for (int mt = 0; mt < 2; mt++)
            #pragma unroll
            for (int nt = 0; nt < 3; nt++)
                acc[mt][nt] = __builtin_amdgcn_mfma_f32_16x16x32_f16(a[mt], b[nt], acc[mt][nt], 0, 0, 0);
    }

    if (z < 2) {   // Q or K: RoPE epilogue
        f16_t* dst = (z == 0) ? Q16 : K16;
        // invf in revolutions: theta^{-(d%8)/8} / (2*pi)
        const float invf_rev = exp2f(-1.6609640474436813f * (float)(n & 7))
                             * 0.15915494309189535f;
        #pragma unroll
        for (int mt = 0; mt < 2; mt++) {
            #pragma unroll
            for (int r = 0; r < 4; r++) {
                int m = m0 + mt*16 + quad*4 + r;
                int bb = m >> 11, s = m & (SEQ - 1);
                float rev = (float)s * invf_rev;
                float fr = rev - floorf(rev);
                float sn = __builtin_amdgcn_sinf(fr);   // sin(2*pi*fr)
                float c  = __builtin_amdgcn_cosf(fr);
                #pragma unroll
                for (int nt = 0; nt < 3; nt++) {
                    float own = acc[mt][nt][r];
                    float par = __shfl_xor(own, 8, 64);
                    float val = (n & 8) ? fmaf(own, c, par*sn) : fmaf(own, c, -par*sn);
                    if (z == 0) val *= 0.36067376022224085f;  // 0.25 * log2(e)
                    int head = (n0 >> 4) + nt;
                    dst[((size_t)((bb*NHEADS + head)*SEQ) + s)*HEAD_D + n] = (f16_t)val;
                }
            }
        }
    } else {       // V: transposed tiled store
        #pragma unroll
        for (int mt = 0; mt < 2; mt++)
            #pragma unroll
            for (int nt = 0; nt < 3; nt++)
                #pragma unroll
                for (int r = 0; r < 4; r++) {
                    int m = m0 + mt*16 + quad*4 + r;
                    int bb = m >> 11, s = m & (SEQ - 1);
                    int head = (n0 >> 4) + nt;
                    Vt[(size_t)(bb*NHEADS + head)*(SEQ*HEAD_D)
                       + (size_t)(s >> 4)*256 + n*16 + (s & 15)] = (f16_t)acc[mt][nt][r];
                }
    }
}

__device__ __forceinline__ half4v pack4(const float p[4]) {
    half2v ab = __builtin_bit_cast(half2v, __builtin_amdgcn_cvt_pkrtz(p[0], p[1]));
    half2v cd = __builtin_bit_cast(half2v, __builtin_amdgcn_cvt_pkrtz(p[2], p[3]));
    half4v o; o[0]=ab[0]; o[1]=ab[1]; o[2]=cd[0]; o[3]=cd[1];
    return o;
}

// ---------------------------------------------------------------------------
// K2: flash attention split-K partials — EXACT R0/R9-proven structure
// (10368 units, bulk 16-tile register batch, 2 q-tiles per wave; no swizzle,
// no setprio: R15/R16/R17 variants all measured neutral-to-worse).
// R18 change: partials stored as f16 (acc via pack4/RTZ, l via scalar cvt).
// Halves the accbuf/lbuf round trip 53 MB -> 26.5 MB. Precision: per-lane
// l <= ~600 (f16 rel err 1e-3 -> O err ~2e-5), acc ~ +-30, quantization
// after normalization ~4e-5 — both >=40x below the f16 output quantum that
// bounds absmax anyway. Partials are summed in f32 in attn_red as before.
// ---------------------------------------------------------------------------
__global__ __launch_bounds__(256) void attn_part(
    const f16_t* __restrict__ Q16, const f16_t* __restrict__ K16,
    const f16_t* __restrict__ Vt,
    half4v* __restrict__ accbuf, f16_t* __restrict__ lbuf)
{
    const int unit = blockIdx.x*4 + (threadIdx.x >> 6);   // 0..10367
    const int lane = threadIdx.x & 63;
    const int n = lane & 15, quad = lane >> 4;

    const int bh = unit / 288;
    const int rem = unit - bh*288;
    int g, t0;
    if      (rem < 8)   { g=0; t0=rem;     }
    else if (rem < 24)  { g=1; t0=rem-8;   }
    else if (rem < 48)  { g=2; t0=rem-24;  }
    else if (rem < 80)  { g=3; t0=rem-48;  }
    else if (rem < 120) { g=4; t0=rem-80;  }
    else if (rem < 168) { g=5; t0=rem-120; }
    else if (rem < 224) { g=6; t0=rem-168; }
    else                { g=7; t0=rem-224; }
    const int qd = t0 / (g+1);
    const int qp = 8*g + qd;
    const int chunk = t0 - qd*(g+1);
    const int q0 = qp*32;

    half4v qb0 = *(const half4v*)(Q16 + ((size_t)bh*SEQ + q0 + n)*HEAD_D + quad*4);
    half4v qb1 = *(const half4v*)(Q16 + ((size_t)bh*SEQ + q0 + 16 + n)*HEAD_D + quad*4);
    const f16_t* Kb = K16 + (size_t)bh * SEQ * HEAD_D;
    const f16_t* Vb = Vt  + (size_t)bh * SEQ * HEAD_D;
    const int loff = n*16 + quad*4;

    const float4v zero = {0.f, 0.f, 0.f, 0.f};
    float4v acc0 = zero, acc1 = zero;
    float l0 = 0.f, l1 = 0.f;

    const int lim0 = 2*qp, lim1 = 2*qp + 1;
    const int ktlo = chunk*16;
    const int kthi = min(ktlo + 15, lim1);

    if (ktlo + 15 < lim0) {
        half4v KA[16], VA[16];
        #pragma unroll
        for (int i = 0; i < 16; i++) {
            KA[i] = *(const half4v*)(Kb + (size_t)(ktlo + i)*256 + loff);
            VA[i] = *(const half4v*)(Vb + (size_t)(ktlo + i)*256 + loff);
        }
        #pragma unroll
        for (int i = 0; i < 16; i++) {
            float4v s1 = __builtin_amdgcn_mfma_f32_16x16x16f16(KA[i], qb1, zero, 0, 0, 0);
            float4v s0 = __builtin_amdgcn_mfma_f32_16x16x16f16(KA[i], qb0, zero, 0, 0, 0);
            float p1[4], p0[4];
            #pragma unroll
            for (int r = 0; r < 4; r++) { p1[r] = __builtin_amdgcn_exp2f(s1[r]); p0[r] = __builtin_amdgcn_exp2f(s0[r]); }
            l1 += (p1[0]+p1[1]) + (p1[2]+p1[3]);
            l0 += (p0[0]+p0[1]) + (p0[2]+p0[3]);
            acc1 = __builtin_amdgcn_mfma_f32_16x16x16f16(VA[i], pack4(p1), acc1, 0, 0, 0);
            acc0 = __builtin_amdgcn_mfma_f32_16x16x16f16(VA[i], pack4(p0), acc0, 0, 0, 0);
        }
    } else {
        int kt = ktlo;
        half4v ka = *(const half4v*)(Kb + (size_t)kt*256 + loff);
        half4v va = *(const half4v*)(Vb + (size_t)kt*256 + loff);
        for (; kt <= kthi; kt++) {
            half4v kan, van;
            if (kt < kthi) {
                kan = *(const half4v*)(Kb + (size_t)(kt+1)*256 + loff);
                van = *(const half4v*)(Vb + (size_t)(kt+1)*256 + loff);
            }
            {   // tile 1
                float4v s = __builtin_amdgcn_mfma_f32_16x16x16f16(ka, qb1, zero, 0, 0, 0);
                float p[4];
                #pragma unroll
                for (int r = 0; r < 4; r++) {
                    float e = __builtin_amdgcn_exp2f(s[r]);
                    p[r] = (kt == lim1 && quad*4 + r > n) ? 0.0f : e;
                }
                l1 += (p[0]+p[1]) + (p[2]+p[3]);
                acc1 = __builtin_amdgcn_mfma_f32_16x16x16f16(va, pack4(p), acc1, 0, 0, 0);
            }
            if (kt <= lim0) {   // tile 0
                float4v s = __builtin_amdgcn_mfma_f32_16x16x16f16(ka, qb0, zero, 0, 0, 0);
                float p[4];
                #pragma unroll
                for (int r = 0; r < 4; r++) {
                    float e = __builtin_amdgcn_exp2f(s[r]);
                    p[r] = (kt == lim0 && quad*4 + r > n) ? 0.0f : e;
                }
                l0 += (p[0]+p[1]) + (p[2]+p[3]);
                acc0 = __builtin_amdgcn_mfma_f32_16x16x16f16(va, pack4(p), acc0, 0, 0, 0);
            }
            ka = kan; va = van;
        }
    }

    float a0f[4] = {acc0[0], acc0[1], acc0[2], acc0[3]};
    float a1f[4] = {acc1[0], acc1[1], acc1[2], acc1[3]};
    accbuf[((size_t)unit*2 + 0)*64 + lane] = pack4(a0f);
    accbuf[((size_t)unit*2 + 1)*64 + lane] = pack4(a1f);
    lbuf[((size_t)unit*2 + 0)*64 + lane] = (f16_t)l0;
    lbuf[((size_t)unit*2 + 1)*64 + lane] = (f16_t)l1;
}

// ---------------------------------------------------------------------------
// K3: reduction: one wave per (bh, qp) sums <=8 chunk partials, normalizes,
// writes f16 O. (R9-proven structure; R18: f16 partial loads, f32 accum.)
// ---------------------------------------------------------------------------
__global__ __launch_bounds__(256) void attn_red(
    const half4v* __restrict__ accbuf, const f16_t* __restrict__ lbuf,
    f16_t* __restrict__ Of)
{
    const int wid = blockIdx.x*4 + (threadIdx.x >> 6);    // 0..2303
    const int lane = threadIdx.x & 63;
    const int n = lane & 15, quad = lane >> 4;
    const int bh = wid >> 6, qp = wid & 63;
    const int b = bh / NHEADS, h = bh - b*NHEADS;
    const int g = qp >> 3, j = qp & 7;
    const int nch = g + 1;
    const int ubase = bh*288 + qp + 4*g*(g-1) + g*j;

    #pragma unroll
    for (int t = 0; t < 2; t++) {
        float4 a = {0.f, 0.f, 0.f, 0.f};
        float l = 0.f;
        for (int c = 0; c < nch; c++) {
            size_t idx = ((size_t)(ubase + c)*2 + t)*64 + lane;
            half4v v = accbuf[idx];
            a.x += (float)v[0]; a.y += (float)v[1];
            a.z += (float)v[2]; a.w += (float)v[3];
            l += (float)lbuf[idx];
        }
        l += __shfl_xor(l, 16, 64);
        l += __shfl_xor(l, 32, 64);
        float inv = 1.0f / l;
        half4v o;
        o[0]=(f16_t)(a.x*inv); o[1]=(f16_t)(a.y*inv);
        o[2]=(f16_t)(a.z*inv); o[3]=(f16_t)(a.w*inv);
        *(half4v*)(Of + (size_t)(b*SEQ + qp*32 + t*16 + n)*H_DIM + h*HEAD_D + quad*4) = o;
    }
}

// ---------------------------------------------------------------------------
// K4: output projection via MFMA (R9-proven). Tile M=32 x N=48, grid (6,128).
// ---------------------------------------------------------------------------
__global__ __launch_bounds__(64) void out_mfma(
    const f16_t* __restrict__ Of, const f16_t* __restrict__ Wo16,
    float* __restrict__ C)
{
    const int n0 = blockIdx.x * 48;
    const int m0 = blockIdx.y * 32;
    const int lane = threadIdx.x & 63;
    const int n = lane & 15, quad = lane >> 4;

    float4v acc[2][3];
    #pragma unroll
    for (int mt = 0; mt < 2; mt++)
        #pragma unroll
        for (int nt = 0; nt < 3; nt++)
            acc[mt][nt] = (float4v){0.f,0.f,0.f,0.f};

    for (int k0 = 0; k0 < H_DIM; k0 += 32) {
        half8v a[2], b[3];
        #pragma unroll
        for (int mt = 0; mt < 2; mt++)
            a[mt] = *(const half8v*)(Of + (size_t)(m0 + mt*16 + n)*H_DIM + k0 + quad*8);
        #pragma unroll
        for (int nt = 0; nt < 3; nt++)
            b[nt] = *(const half8v*)(Wo16 + (size_t)(n0 + nt*16 + n)*H_DIM + k0 + quad*8);
        #pragma unroll
        for (int mt = 0; mt < 2; mt++)
            #pragma unroll
            for (int nt = 0; nt < 3; nt++)
                acc[mt][nt] = __builtin_amdgcn_mfma_f32_16x16x32_f16(a[mt], b[nt], acc[mt][nt], 0, 0, 0);
    }
    #pragma unroll
    for (int mt = 0; mt < 2; mt++)
        #pragma unroll
        for (int nt = 0; nt < 3; nt++)
            #pragma unroll
            for (int r = 0; r < 4; r++) {
                int m = m0 + mt*16 + quad*4 + r;
                C[(size_t)m*H_DIM + n0 + nt*16 + n] = acc[mt][nt][r];
            }
}

// ---------------------------------------------------------------------------
extern "C" void kernel_launch(void* const* d_in, const int* in_sizes, int n_in,
                              void* d_out, int out_size, void* d_ws, size_t ws_size,
                              hipStream_t stream)
{
    const float* Xh = (const float*)d_in[0];
    const float* Wq = (const float*)d_in[1];
    const float* Wk = (const float*)d_in[2];
    const float* Wv = (const float*)d_in[3];
    const float* Wo = (const float*)d_in[4];
    float* out = (float*)d_out;

    f16_t* Xf  = (f16_t*)d_ws;                  // XCNT
    f16_t* Wf  = Xf + XCNT;                     // 4*WCNT
    f16_t* Q16 = Wf + 4*(size_t)WCNT;           // XCNT
    f16_t* K16 = Q16 + XCNT;                    // XCNT
    f16_t* Vt  = K16 + XCNT;                    // XCNT
    f16_t* Of  = Vt + XCNT;                     // XCNT
    half4v* accbuf = (half4v*)(Of + XCNT);      // NUNITS*2*64 half4v (8 B)
    f16_t*  lbuf   = (f16_t*)(accbuf + (size_t)NUNITS*2*64);

    const int total4 = (XCNT + 4*WCNT)/4;
    cvt_f16<<<dim3((total4 + 255)/256), 256, 0, stream>>>(Xh, Wq, Wk, Wv, Wo, Xf, Wf);
    qkv_mfma<<<dim3(18, 128), 64, 0, stream>>>(Xf, Wf, Q16, K16, Vt);
    attn_part<<<dim3(NUNITS/4), 256, 0, stream>>>(Q16, K16, Vt, accbuf, lbuf);
    attn_red<<<dim3(NQUNITS/4), 256, 0, stream>>>(accbuf, lbuf, Of);
    out_mfma<<<dim3(6, 128), 64, 0, stream>>>(Of, Wf + 3*(size_t)WCNT, out);
}